// Round 1
// 514.483 us; speedup vs baseline: 1.0433x; 1.0433x over previous
//
#include <hip/hip_runtime.h>
#include <hip/hip_bf16.h>
#include <math.h>

// Problem constants
#define BB 4
#define NSEQ 4096
#define DD 1024
#define HH 16
#define HD 64
#define MROWS (BB * NSEQ)   // 16384

typedef __attribute__((ext_vector_type(8))) short short8;
typedef float v4f __attribute__((ext_vector_type(4)));
typedef unsigned short u16;

typedef __attribute__((address_space(1))) const void gconst_void;
typedef __attribute__((address_space(3))) void lds_void_t;

__device__ __constant__ int SHIFTS[24] = {0,1,2,3,4,6,8,12,16,24,32,48,64,96,128,192,256,384,512,768,1024,1536,2048,3072};

__device__ inline u16 f2bf(float f) {
    unsigned u = __float_as_uint(f);
    unsigned r = u + 0x7fffu + ((u >> 16) & 1u);
    return (u16)(r >> 16);
}
__device__ inline float bf2f(u16 h) {
    return __uint_as_float(((unsigned)h) << 16);
}
__device__ inline void gl2lds16(const u16* g, u16* l) {
    // async global->LDS DMA, 16B/lane; LDS dest = wave-uniform base + lane*16
    __builtin_amdgcn_global_load_lds((gconst_void*)g, (lds_void_t*)l, 16, 0, 0);
}

// ---------------- prep: merged 24-tap coef table per head, coupling softmax, skip sigmoid ----------------
__global__ void prep_kernel(const float* __restrict__ scale_gain, const float* __restrict__ skip_w,
                            const float* __restrict__ coupling, float* __restrict__ coefTab,
                            float* __restrict__ coupS, float* __restrict__ swbuf) {
    const float D4T[4] = {0.4829629131445341f, 0.8365163037378079f, 0.2241438680420134f, -0.1294095225512604f};
    int t = threadIdx.x;
    if (t < 2) swbuf[t] = 1.0f / (1.0f + expf(-skip_w[t]));
    if (t < 16) {
        float m = -1e30f;
        for (int j = 0; j < 16; j++) m = fmaxf(m, coupling[t * 16 + j]);
        float s = 0.f, e[16];
        for (int j = 0; j < 16; j++) { e[j] = expf(coupling[t * 16 + j] - m); s += e[j]; }
        for (int j = 0; j < 16; j++) coupS[t * 16 + j] = e[j] / s;
        float g[11];
        m = -1e30f;
        for (int j = 0; j < 11; j++) m = fmaxf(m, scale_gain[j * 16 + t]);
        s = 0.f;
        for (int j = 0; j < 11; j++) { g[j] = expf(scale_gain[j * 16 + t] - m); s += g[j]; }
        for (int j = 0; j < 11; j++) g[j] /= s;
        float cf[24];
        for (int i = 0; i < 24; i++) cf[i] = 0.f;
        for (int j = 0; j < 11; j++) {
            int d = 1 << j;
            for (int tt = 0; tt < 4; tt++) {
                int sh = (3 - tt) * d;
                for (int i = 0; i < 24; i++) {
                    if (SHIFTS[i] == sh) { cf[i] += g[j] * D4T[tt]; break; }
                }
            }
        }
        for (int i = 0; i < 24; i++) coefTab[t * 24 + i] = cf[i];
    }
}

// ---------------- bfuse[n] = bqkv_q @ Wgate + bgate (fp32) ----------------
__global__ __launch_bounds__(256) void bfuse_kernel(const float* __restrict__ bqkv, const float* __restrict__ Wgate,
                                                    const float* __restrict__ bgate, float* __restrict__ bfuse) {
    __shared__ float part[4][64];
    int nloc = threadIdx.x & 63, strip = threadIdx.x >> 6;
    int n = blockIdx.x * 64 + nloc;
    float s = 0.f;
    for (int j = strip * 256; j < strip * 256 + 256; j++)
        s += bqkv[j] * Wgate[(long)j * 1024 + n];
    part[strip][nloc] = s;
    __syncthreads();
    if (strip == 0)
        bfuse[n] = bgate[n] + part[0][nloc] + part[1][nloc] + part[2][nloc] + part[3][nloc];
}

// ---------------- cast x fp32 -> bf16 ----------------
__global__ __launch_bounds__(256) void cast_x_kernel(const float* __restrict__ x, u16* __restrict__ xb) {
    long i = ((long)blockIdx.x * 256 + threadIdx.x) * 8;
    float4 f0 = *(const float4*)&x[i];
    float4 f1 = *(const float4*)&x[i + 4];
    u16 o[8];
    o[0] = f2bf(f0.x); o[1] = f2bf(f0.y); o[2] = f2bf(f0.z); o[3] = f2bf(f0.w);
    o[4] = f2bf(f1.x); o[5] = f2bf(f1.y); o[6] = f2bf(f1.z); o[7] = f2bf(f1.w);
    *(uint4*)&xb[i] = *(uint4*)o;
}

// ---------------- transpose + cast: W fp32 [rows][ldw] -> WT bf16 [cols][ldt] ----------------
__global__ __launch_bounds__(256) void transpose_cast(const float* __restrict__ W, long ldw,
                                                      u16* __restrict__ WT, long ldt) {
    __shared__ float tile[32][33];
    int tx = threadIdx.x, ty = threadIdx.y;    // 32 x 8
    long x = (long)blockIdx.x * 32 + tx;
    long y0 = (long)blockIdx.y * 32;
    for (int r = 0; r < 32; r += 8)
        tile[ty + r][tx] = W[(y0 + ty + r) * ldw + x];
    __syncthreads();
    for (int r = 0; r < 32; r += 8)
        WT[((long)blockIdx.x * 32 + ty + r) * ldt + y0 + tx] = f2bf(tile[tx][ty + r]);
}

// ---------------- cast q-columns of Wqkv (fp32, ld 3072) -> WqC bf16 [1024][1024] ----------------
__global__ __launch_bounds__(256) void cast_q_kernel(const float* __restrict__ Wqkv, u16* __restrict__ WqC) {
    long i = ((long)blockIdx.x * 256 + threadIdx.x) * 4;
    int row = (int)(i >> 10);
    int col = (int)(i & 1023);
    float4 f = *(const float4*)&Wqkv[(long)row * 3072 + col];
    ushort4 o;
    o.x = f2bf(f.x); o.y = f2bf(f.y); o.z = f2bf(f.z); o.w = f2bf(f.w);
    *(ushort4*)&WqC[i] = o;
}

// ======== old GEMM core (kept for the small 1024^3 weight-fuse GEMM): 128x128 tile, 4 waves ========
#define GEMM_PRE()                                                                  \
    __shared__ u16 As[128 * 32];                                                    \
    __shared__ u16 Bs[128 * 32];                                                    \
    const int tid = threadIdx.x;                                                    \
    const int wave = tid >> 6, lane = tid & 63;                                     \
    const int wm = wave >> 1, wn = wave & 1;                                        \
    const int lrow = lane & 15, kq = lane >> 4;                                     \
    const long m0 = (long)blockIdx.y * 128, n0 = (long)blockIdx.x * 128;            \
    const int r0 = wave * 32 + (lane >> 2);                                         \
    const int sg = (lane & 3) ^ ((r0 >> 1) & 3);                                    \
    const u16* a0 = A + (m0 + r0) * lda + sg * 8;                                   \
    const u16* a1 = a0 + 16 * lda;                                                  \
    const u16* b0 = BT + (n0 + r0) * ldb + sg * 8;                                  \
    const u16* b1 = b0 + 16 * ldb;                                                  \
    u16* la0 = &As[(wave * 32) * 32];                                               \
    u16* la1 = &As[(wave * 32 + 16) * 32];                                          \
    u16* lb0 = &Bs[(wave * 32) * 32];                                               \
    u16* lb1 = &Bs[(wave * 32 + 16) * 32];                                          \
    const int acol = (kq ^ ((lrow >> 1) & 3)) * 8;                                  \
    v4f acc[4][4];                                                                  \
    _Pragma("unroll") for (int i = 0; i < 4; i++)                                   \
        _Pragma("unroll") for (int j = 0; j < 4; j++)                               \
            acc[i][j] = (v4f){0.f, 0.f, 0.f, 0.f};                                  \
    for (int k0 = 0; k0 < K; k0 += 32) {                                            \
        gl2lds16(a0 + k0, la0);                                                     \
        gl2lds16(a1 + k0, la1);                                                     \
        gl2lds16(b0 + k0, lb0);                                                     \
        gl2lds16(b1 + k0, lb1);                                                     \
        __syncthreads();                                                            \
        short8 af[4], bf[4];                                                        \
        _Pragma("unroll") for (int i = 0; i < 4; i++)                               \
            af[i] = *(const short8*)&As[(wm * 64 + i * 16 + lrow) * 32 + acol];     \
        _Pragma("unroll") for (int i = 0; i < 4; i++)                               \
            bf[i] = *(const short8*)&Bs[(wn * 64 + i * 16 + lrow) * 32 + acol];     \
        _Pragma("unroll") for (int im = 0; im < 4; im++)                            \
            _Pragma("unroll") for (int in = 0; in < 4; in++)                        \
                acc[im][in] = __builtin_amdgcn_mfma_f32_16x16x32_bf16(af[im], bf[in], acc[im][in], 0, 0, 0); \
        __syncthreads();                                                            \
    }

// ---------------- gemm2: single-output variant (CMODE: 0 = fp32 out, 1 = bf16 out) ----------------
template <int CMODE>
__global__ __launch_bounds__(256) void gemm2(const u16* __restrict__ A, long lda,
                                             const u16* __restrict__ BT, long ldb, int K,
                                             const float* __restrict__ bias,
                                             void* __restrict__ Cptr, long ldc) {
    GEMM_PRE()
#pragma unroll
    for (int im = 0; im < 4; im++) {
#pragma unroll
        for (int in = 0; in < 4; in++) {
            long row = m0 + wm * 64 + im * 16 + kq * 4;
            long col = n0 + wn * 64 + in * 16 + lrow;
            float bv = bias ? bias[col] : 0.f;
#pragma unroll
            for (int i = 0; i < 4; i++) {
                float val = acc[im][in][i] + bv;
                long idx = (row + i) * ldc + col;
                if (CMODE == 0) ((float*)Cptr)[idx] = val;
                else            ((u16*)Cptr)[idx] = f2bf(val);
            }
        }
    }
}

// ======== NEW pipelined 256x256 GEMM engine ========
// 8 waves (2M x 4N), BK=32, 4-deep LDS tile rotation (128 KB), counted vmcnt
// (never 0 in steady state), raw s_barrier (1 per K-step), setprio around MFMA.
// BK=32 -> 64B LDS rows -> frag ds_read_b128 pattern is structurally uniform
// (8 lanes / 16B bank-group): linear layout, no swizzle, gl2lds dest stays legal.
//
// Pipeline invariants (race-freedom):
//  - tile t lives in buf t&3; STAGE(t+3) issued in iter t targets buf (t-1)&3,
//    whose reads all retired before the end-of-(t-1) barrier (lgkmcnt enforced
//    by MFMA consumption), and issue happens only after that barrier.
//  - end-of-iter-t wait allows loads of tiles {t+2,t+3} (8) to stay in flight;
//    tile t+1 is guaranteed landed (vmcnt retires in order) before the barrier.
#define WAITV(N) asm volatile("s_waitcnt vmcnt(" #N ")" ::: "memory")

template <int CMODE>   // 0 = fp32 out + bias; 2 = fused kv/gate epilogue
__global__ __launch_bounds__(512, 2) void gemm256(const u16* __restrict__ A, long lda,
                                                  const u16* __restrict__ BT, long ldb, int K,
                                                  const float* __restrict__ bias,
                                                  const float* __restrict__ bias2,
                                                  void* __restrict__ C0, void* __restrict__ C1,
                                                  long ldc) {
    __shared__ u16 smem[4 * 2 * 8192];   // 128 KB: [buf 0..3][A|B][256 rows x 32 k]
    const int tid = threadIdx.x;
    const int wv = tid >> 6, lane = tid & 63;
    const int wm = wv >> 2, wn = wv & 3;          // 2 x 4 wave grid; wave tile 128 x 64
    const int lrow = lane & 15, kq = lane >> 4;
    const long m0 = (long)blockIdx.y * 256, n0 = (long)blockIdx.x * 256;

    // staging: wave wv owns rows wv*32 .. wv*32+31 of both tiles (2 calls of 16 rows each)
    const int srow = wv * 32 + (lane >> 2);
    const int scol = (lane & 3) * 8;
    const u16* gA0 = A + (m0 + srow) * lda + scol;
    const u16* gA1 = gA0 + 16 * lda;
    const u16* gB0 = BT + (n0 + srow) * ldb + scol;
    const u16* gB1 = gB0 + 16 * ldb;
    const int sb = wv * 32 * 32;                  // u16 offset of wave's stage region in a tile

    const int aoff = (wm * 128 + lrow) * 32 + kq * 8;
    const int boff = (wn * 64 + lrow) * 32 + kq * 8;

    v4f acc[8][4];
#pragma unroll
    for (int i = 0; i < 8; i++)
#pragma unroll
        for (int j = 0; j < 4; j++) acc[i][j] = (v4f){0.f, 0.f, 0.f, 0.f};

    const int NT = K >> 5;   // K-tiles of 32 (requires K >= 96; K == 1024 here)

#define STAGE256(tt) {                                              \
        const int _kk = (tt) << 5;                                  \
        u16* _p = &smem[(((tt) & 3) * 2) * 8192 + sb];              \
        gl2lds16(gA0 + _kk, _p);                                    \
        gl2lds16(gA1 + _kk, _p + 512);                              \
        gl2lds16(gB0 + _kk, _p + 8192);                             \
        gl2lds16(gB1 + _kk, _p + 8192 + 512); }

    STAGE256(0)
    STAGE256(1)
    STAGE256(2)
    WAITV(8);                        // 12 issued, <=8 outstanding -> tile 0 landed
    __builtin_amdgcn_s_barrier();

    for (int t = 0; t < NT; ++t) {
        if (t + 3 < NT) STAGE256(t + 3)          // issue-early; buffer freed at end of t-1
        const u16* Ab = &smem[((t & 3) * 2) * 8192];
        const u16* Bb = Ab + 8192;
        short8 af[8], bf[4];
#pragma unroll
        for (int i = 0; i < 8; i++) af[i] = *(const short8*)&Ab[aoff + i * 512];
#pragma unroll
        for (int j = 0; j < 4; j++) bf[j] = *(const short8*)&Bb[boff + j * 512];
        __builtin_amdgcn_s_setprio(1);
#pragma unroll
        for (int i = 0; i < 8; i++)
#pragma unroll
            for (int j = 0; j < 4; j++)
                acc[i][j] = __builtin_amdgcn_mfma_f32_16x16x32_bf16(af[i], bf[j], acc[i][j], 0, 0, 0);
        __builtin_amdgcn_s_setprio(0);
        if (t + 3 < NT)      { WAITV(8); }       // tiles t+2,t+3 may stay in flight
        else if (t + 2 < NT) { WAITV(4); }       // only t+2 issued after t+1
        else if (t + 1 < NT) { WAITV(0); }       // nothing issued after t+1: drain
        __builtin_amdgcn_s_barrier();
    }
#undef STAGE256

    // ---- epilogue ----
    if (CMODE == 0) {
        float* C = (float*)C0;
#pragma unroll
        for (int im = 0; im < 8; im++) {
#pragma unroll
            for (int in = 0; in < 4; in++) {
                long row = m0 + wm * 128 + im * 16 + kq * 4;
                long col = n0 + wn * 64 + in * 16 + lrow;
                float bv = bias ? bias[col] : 0.f;
#pragma unroll
                for (int i = 0; i < 4; i++)
                    C[(row + i) * ldc + col] = acc[im][in][i] + bv;
            }
        }
    } else {
        u16* kvC = (u16*)C0;
        u16* gateC = (u16*)C1;
        const bool isGate = (n0 >= 2048);        // BN=256 aligns with the 2048 split
#pragma unroll
        for (int im = 0; im < 8; im++) {
#pragma unroll
            for (int in = 0; in < 4; in++) {
                long row = m0 + wm * 128 + im * 16 + kq * 4;
                long col = n0 + wn * 64 + in * 16 + lrow;
                if (!isGate) {
                    float bv = bias[col];
#pragma unroll
                    for (int i = 0; i < 4; i++)
                        kvC[(row + i) * 2048 + col] = f2bf(acc[im][in][i] + bv);
                } else {
                    long gc = col - 2048;
                    float bv = bias2[gc];
#pragma unroll
                    for (int i = 0; i < 4; i++) {
                        float sgm = 1.0f / (1.0f + expf(-(acc[im][in][i] + bv)));
                        gateC[(row + i) * 1024 + gc] = f2bf(sgm);
                    }
                }
            }
        }
    }
}

// ---------------- kmag[bh][n] = ||k(row,h)|| ----------------
__global__ __launch_bounds__(256) void kmag_kernel(const u16* __restrict__ kv, float* __restrict__ kmag) {
    int tid = threadIdx.x;
    int wave = tid >> 6, lane = tid & 63;
    long gid = (long)blockIdx.x * 4 + wave;   // 0 .. 16384*16-1
    int row = (int)(gid >> 4);
    int h = (int)(gid & 15);
    float kvl = bf2f(kv[(long)row * 2048 + h * 64 + lane]);
    float ss = kvl * kvl;
#pragma unroll
    for (int m = 32; m > 0; m >>= 1) ss += __shfl_xor(ss, m, 64);
    if (lane == 0) {
        int b = row >> 12;
        int n = row & 4095;
        kmag[((long)b * HH + h) * NSEQ + n] = sqrtf(ss);
    }
}

// ---------------- foldv: field_t[bh][cg][n][4] = v * kmag, transposed via LDS tile ----------------
__global__ __launch_bounds__(256) void foldv_kernel(const u16* __restrict__ kv,
                                                    const float* __restrict__ kmag,
                                                    u16* __restrict__ field_t) {
    __shared__ u16 tile[64][72];   // pad 72: 144B row stride (16B-aligned, 4-bank rotation)
    int bh = blockIdx.y;           // 0..63
    int n0 = blockIdx.x * 64;      // 0..4032
    int b = bh >> 4, h = bh & 15;
    int t = threadIdx.x;

    // phase 1: read v rows (coalesced 128B per 4 lanes), scale by kmag, store to LDS tile
    {
        int r = t >> 2;            // row within tile (0..63)
        int c0 = (t & 3) * 16;     // 16 channels
        int n = n0 + r;
        const u16* src = kv + ((long)(b * NSEQ + n)) * 2048 + 1024 + h * 64 + c0;
        uint4 u0 = *(const uint4*)src;
        uint4 u1 = *(const uint4*)(src + 8);
        float km = kmag[(long)bh * NSEQ + n];
        u16 in[16], o[16];
        *(uint4*)&in[0] = u0;
        *(uint4*)&in[8] = u1;
#pragma unroll
        for (int i = 0; i < 16; i++) o[i] = f2bf(bf2f(in[i]) * km);
        *(uint4*)&tile[r][c0] = *(uint4*)&o[0];
        *(uint4*)&tile[r][c0 + 8] = *(uint4*)&o[8];
    }
    __syncthreads();

    // phase 2: write interleaved [cg][n][4] chunks (coalesced 32B/lane)
    {
        int cg = t >> 4;           // 0..15
        int q = t & 15;            // 0..15 -> 4 rows each
        u16 o[16];
#pragma unroll
        for (int j = 0; j < 4; j++) {
            int r = q * 4 + j;
            *(ushort4*)&o[j * 4] = *(const ushort4*)&tile[r][cg * 4];
        }
        u16* dst = field_t + (((long)bh * 16 + cg) * NSEQ + n0 + q * 4) * 4;
        *(uint4*)&dst[0] = *(uint4*)&o[0];
        *(uint4*)&dst[8] = *(uint4*)&o[8];
    }
}

// ---------------- pyramid: 24-tap merged dilated causal conv from field_t ----------------
__global__ __launch_bounds__(512) void pyramid_kernel(const u16* __restrict__ field_t,
                                                      const float* __restrict__ coefTab,
                                                      u16* __restrict__ accp) {
    __shared__ u16 lds4[NSEQ * 4];  // 32KB: 4096 rows x 4 channels, bf16
    int blk = blockIdx.x;
    int bh = blk >> 4;       // 0..63 : b*16+h
    int cg = blk & 15;       // channel group of 4
    int hd0 = cg * 4;
    int h = bh & 15;
    int tid = threadIdx.x;

    float cf[24];
#pragma unroll
    for (int i = 0; i < 24; i++) cf[i] = coefTab[h * 24 + i];

    // stage: contiguous 32 KB copy (fully coalesced 16B per lane)
    const u16* src = field_t + ((long)bh * 16 + cg) * NSEQ * 4;
#pragma unroll
    for (int k = 0; k < 4; k++) {
        long e = ((long)k * 512 + tid) * 8;
        *(uint4*)&lds4[e] = *(const uint4*)&src[e];
    }
    __syncthreads();

    u16* dst = accp + (long)bh * NSEQ * HD + hd0;
    for (int i = 0; i < 8; i++) {
        int n = tid + i * 512;
        float ax = 0.f, ay = 0.f, az = 0.f, aw = 0.f;
#pragma unroll
        for (int tp = 0; tp < 24; tp++) {
            int s = SHIFTS[tp];
            if (n >= s) {
                const ushort4 f = *(const ushort4*)&lds4[(n - s) * 4];
                float c = cf[tp];
                ax += c * bf2f(f.x); ay += c * bf2f(f.y);
                az += c * bf2f(f.z); aw += c * bf2f(f.w);
            }
        }
        ushort4 o;
        o.x = f2bf(ax); o.y = f2bf(ay); o.z = f2bf(az); o.w = f2bf(aw);
        *(ushort4*)&dst[(long)n * HD] = o;
    }
}

// ---------------- couple: sparse skips + head coupling + gate -> A3 bf16 ----------------
__global__ __launch_bounds__(256) void couple_kernel(const u16* __restrict__ accp,
                                                     const u16* __restrict__ gate,
                                                     const float* __restrict__ coupS,
                                                     const float* __restrict__ swbuf,
                                                     u16* __restrict__ A3) {
    __shared__ float tmp[DD];
    __shared__ float cp[256];
    int row = blockIdx.x;
    int b = row >> 12;
    int n = row & 4095;
    int tid = threadIdx.x;
    float sw0 = swbuf[0], sw1 = swbuf[1];
    cp[tid] = coupS[tid];

    int e = tid * 4;
    int j = e >> 6;      // head
    int hd = e & 63;
    const u16* base = accp + (((long)b * HH + j) * NSEQ + n) * HD + hd;
    ushort4 v0 = *(const ushort4*)base;
    float vx = bf2f(v0.x), vy = bf2f(v0.y), vz = bf2f(v0.z), vw = bf2f(v0.w);
    if (n >= 512) {
        ushort4 s1 = *(const ushort4*)(base - 512 * HD);
        vx += sw0 * bf2f(s1.x); vy += sw0 * bf2f(s1.y);
        vz += sw0 * bf2f(s1.z); vw += sw0 * bf2f(s1.w);
    }
    if (n >= 1024) {
        ushort4 s2 = *(const ushort4*)(base - 1024 * HD);
        vx += sw1 * bf2f(s2.x); vy += sw1 * bf2f(s2.y);
        vz += sw1 * bf2f(s2.z); vw += sw1 * bf2f(s2.w);
    }
    tmp[e] = vx; tmp[e + 1] = vy; tmp[e + 2] = vz; tmp[e + 3] = vw;
    __syncthreads();

    float ox = 0.f, oy = 0.f, oz = 0.f, ow = 0.f;
#pragma unroll
    for (int jj = 0; jj < 16; jj++) {
        float c = cp[j * 16 + jj];
        ox += c * tmp[jj * 64 + hd];
        oy += c * tmp[jj * 64 + hd + 1];
        oz += c * tmp[jj * 64 + hd + 2];
        ow += c * tmp[jj * 64 + hd + 3];
    }
    const ushort4 g = *(const ushort4*)&gate[(long)row * DD + e];
    ox *= bf2f(g.x); oy *= bf2f(g.y); oz *= bf2f(g.z); ow *= bf2f(g.w);
    ushort4 o;
    o.x = f2bf(ox); o.y = f2bf(oy); o.z = f2bf(oz); o.w = f2bf(ow);
    *(ushort4*)&A3[(long)row * DD + e] = o;
}

// ---------------- launch ----------------
extern "C" void kernel_launch(void* const* d_in, const int* in_sizes, int n_in,
                              void* d_out, int out_size, void* d_ws, size_t ws_size,
                              hipStream_t stream) {
    const float* x        = (const float*)d_in[0];   // [16384][1024]
    const float* Wqkv     = (const float*)d_in[1];   // [1024][3072]
    const float* bqkv     = (const float*)d_in[2];   // [3072]
    const float* Wout     = (const float*)d_in[3];   // [1024][1024]
    const float* bout     = (const float*)d_in[4];   // [1024]
    const float* Wgate    = (const float*)d_in[5];   // [1024][1024]
    const float* bgate    = (const float*)d_in[6];   // [1024]
    const float* scale_g  = (const float*)d_in[7];   // [11][16]
    const float* skip_w   = (const float*)d_in[8];   // [2]
    const float* coupling = (const float*)d_in[9];   // [16][16]

    char* ws = (char*)d_ws;
    size_t off = 0;
    auto alloc = [&](size_t bytes) { char* p = ws + off; off += (bytes + 255) & ~(size_t)255; return p; };

    u16*   kv      = (u16*)alloc((size_t)MROWS * 2048 * 2);         // 67.1 MB (k: cols 0..1023, v: 1024..2047)
    u16*   gate    = (u16*)alloc((size_t)MROWS * DD * 2);           // 33.6 MB
    u16*   field_t = (u16*)alloc((size_t)BB * HH * NSEQ * HD * 2);  // 33.6 MB (also aliased as xb early)
    u16*   WkvT    = (u16*)alloc((size_t)2048 * 1024 * 2);          // 4.2 MB   } contiguous: fused B^T
    u16*   WfuseT  = (u16*)alloc((size_t)1024 * 1024 * 2);          // 2.1 MB   } rows 2048..3071
    u16*   WgateT  = (u16*)alloc((size_t)1024 * 1024 * 2);          // 2.1 MB
    u16*   WoutT   = (u16*)alloc((size_t)1024 * 1024 * 2);          // 2.1 MB
    u16*   WqC     = (u16*)alloc((size_t)1024 * 1024 * 2);          // 2.1 MB
    float* kmag    = (float*)alloc((size_t)BB * HH * NSEQ * 4);     // 1.0 MB
    float* bfuse   = (float*)alloc(1024 * 4);
    float* coefT   = (float*)alloc(16 * 24 * 4);
    float* coupS   = (float*)alloc(256 * 4);
    float* swbuf   = (float*)alloc(2 * 4);
    // aliases (all within already-counted regions):
    u16*   xb   = field_t;                              // x cast; dead before foldv writes field_t
    u16*   accp = kv;                                   // pyramid out: kv dead after foldv
    u16*   A3   = kv + (size_t)BB * HH * NSEQ * HD;     // second half of kv region
    // total ~147 MB

    // 0) cast x -> bf16
    cast_x_kernel<<<(MROWS * DD) / (256 * 8), 256, 0, stream>>>(x, xb);

    // 1) small prep
    prep_kernel<<<1, 64, 0, stream>>>(scale_g, skip_w, coupling, coefT, coupS, swbuf);
    bfuse_kernel<<<16, 256, 0, stream>>>(bqkv, Wgate, bgate, bfuse);

    // 2) weight transposes/casts (fp32 -> bf16, B^T layout for MFMA)
    transpose_cast<<<dim3(64, 32), dim3(32, 8), 0, stream>>>(Wqkv + 1024, 3072, WkvT, 1024);  // k,v cols
    transpose_cast<<<dim3(32, 32), dim3(32, 8), 0, stream>>>(Wgate, 1024, WgateT, 1024);
    transpose_cast<<<dim3(32, 32), dim3(32, 8), 0, stream>>>(Wout, 1024, WoutT, 1024);
    cast_q_kernel<<<1024, 256, 0, stream>>>(Wqkv, WqC);                                       // q cols, no transpose

    // 3) WfuseT[g][k_in] = sum_j WgateT[g][j] * WqC[k_in][j]  (= (Wqkv_q @ Wgate)^T)
    //    small grid: stays on the 128^2 engine (64 blocks > 16 blocks of the 256^2 engine)
    gemm2<1><<<dim3(8, 8), 256, 0, stream>>>(WgateT, 1024, WqC, 1024, 1024,
                                             (const float*)nullptr, WfuseT, 1024);

    // 4) fused: [kv | gate] = xb @ [Wkv | Wfuse] (+bias; sigmoid on gate part) -- pipelined 256^2 engine
    gemm256<2><<<dim3(12, 64), 512, 0, stream>>>(xb, 1024, WkvT, 1024, 1024,
                                                 bqkv + 1024, bfuse, kv, gate, 0);

    // 5) kmag
    kmag_kernel<<<(MROWS * HH) / 4, 256, 0, stream>>>(kv, kmag);

    // 6) foldv: field_t[bh][cg][n][4] = v * kmag  (xb dead now)
    foldv_kernel<<<dim3(64, 64), 256, 0, stream>>>(kv, kmag, field_t);

    // 7) pyramid (24 merged taps) -> accp (kv region; kv dead)
    pyramid_kernel<<<BB * HH * 16, 512, 0, stream>>>(field_t, coefT, accp);

    // 8) skips + coupling + gating -> A3 (upper half of kv region)
    couple_kernel<<<MROWS, 256, 0, stream>>>(accp, gate, coupS, swbuf, A3);

    // 9) out = A3 @ Wout + bout  (fp32 out) -- pipelined 256^2 engine
    gemm256<0><<<dim3(4, 64), 512, 0, stream>>>(A3, 1024, WoutT, 1024, 1024,
                                                bout, (const float*)nullptr, (float*)d_out, nullptr, 1024);
}

// Round 2
// 503.813 us; speedup vs baseline: 1.0654x; 1.0212x over previous
//
#include <hip/hip_runtime.h>
#include <hip/hip_bf16.h>
#include <math.h>

// Problem constants
#define BB 4
#define NSEQ 4096
#define DD 1024
#define HH 16
#define HD 64
#define MROWS (BB * NSEQ)   // 16384

typedef __attribute__((ext_vector_type(8))) short short8;
typedef float v4f __attribute__((ext_vector_type(4)));
typedef unsigned short u16;

typedef __attribute__((address_space(1))) const void gconst_void;
typedef __attribute__((address_space(3))) void lds_void_t;

__device__ __constant__ int SHIFTS[24] = {0,1,2,3,4,6,8,12,16,24,32,48,64,96,128,192,256,384,512,768,1024,1536,2048,3072};

__device__ inline u16 f2bf(float f) {
    unsigned u = __float_as_uint(f);
    unsigned r = u + 0x7fffu + ((u >> 16) & 1u);
    return (u16)(r >> 16);
}
__device__ inline float bf2f(u16 h) {
    return __uint_as_float(((unsigned)h) << 16);
}
__device__ inline void gl2lds16(const u16* g, u16* l) {
    // async global->LDS DMA, 16B/lane; LDS dest = wave-uniform base + lane*16
    __builtin_amdgcn_global_load_lds((gconst_void*)g, (lds_void_t*)l, 16, 0, 0);
}

// ---------------- prep: merged 24-tap coef table per head, coupling softmax, skip sigmoid ----------------
__global__ void prep_kernel(const float* __restrict__ scale_gain, const float* __restrict__ skip_w,
                            const float* __restrict__ coupling, float* __restrict__ coefTab,
                            float* __restrict__ coupS, float* __restrict__ swbuf) {
    const float D4T[4] = {0.4829629131445341f, 0.8365163037378079f, 0.2241438680420134f, -0.1294095225512604f};
    int t = threadIdx.x;
    if (t < 2) swbuf[t] = 1.0f / (1.0f + expf(-skip_w[t]));
    if (t < 16) {
        float m = -1e30f;
        for (int j = 0; j < 16; j++) m = fmaxf(m, coupling[t * 16 + j]);
        float s = 0.f, e[16];
        for (int j = 0; j < 16; j++) { e[j] = expf(coupling[t * 16 + j] - m); s += e[j]; }
        for (int j = 0; j < 16; j++) coupS[t * 16 + j] = e[j] / s;
        float g[11];
        m = -1e30f;
        for (int j = 0; j < 11; j++) m = fmaxf(m, scale_gain[j * 16 + t]);
        s = 0.f;
        for (int j = 0; j < 11; j++) { g[j] = expf(scale_gain[j * 16 + t] - m); s += g[j]; }
        for (int j = 0; j < 11; j++) g[j] /= s;
        float cf[24];
        for (int i = 0; i < 24; i++) cf[i] = 0.f;
        for (int j = 0; j < 11; j++) {
            int d = 1 << j;
            for (int tt = 0; tt < 4; tt++) {
                int sh = (3 - tt) * d;
                for (int i = 0; i < 24; i++) {
                    if (SHIFTS[i] == sh) { cf[i] += g[j] * D4T[tt]; break; }
                }
            }
        }
        for (int i = 0; i < 24; i++) coefTab[t * 24 + i] = cf[i];
    }
}

// ---------------- bfuse[n] = bqkv_q @ Wgate + bgate (fp32) ----------------
__global__ __launch_bounds__(256) void bfuse_kernel(const float* __restrict__ bqkv, const float* __restrict__ Wgate,
                                                    const float* __restrict__ bgate, float* __restrict__ bfuse) {
    __shared__ float part[4][64];
    int nloc = threadIdx.x & 63, strip = threadIdx.x >> 6;
    int n = blockIdx.x * 64 + nloc;
    float s = 0.f;
    for (int j = strip * 256; j < strip * 256 + 256; j++)
        s += bqkv[j] * Wgate[(long)j * 1024 + n];
    part[strip][nloc] = s;
    __syncthreads();
    if (strip == 0)
        bfuse[n] = bgate[n] + part[0][nloc] + part[1][nloc] + part[2][nloc] + part[3][nloc];
}

// ---------------- cast x fp32 -> bf16 ----------------
__global__ __launch_bounds__(256) void cast_x_kernel(const float* __restrict__ x, u16* __restrict__ xb) {
    long i = ((long)blockIdx.x * 256 + threadIdx.x) * 8;
    float4 f0 = *(const float4*)&x[i];
    float4 f1 = *(const float4*)&x[i + 4];
    u16 o[8];
    o[0] = f2bf(f0.x); o[1] = f2bf(f0.y); o[2] = f2bf(f0.z); o[3] = f2bf(f0.w);
    o[4] = f2bf(f1.x); o[5] = f2bf(f1.y); o[6] = f2bf(f1.z); o[7] = f2bf(f1.w);
    *(uint4*)&xb[i] = *(uint4*)o;
}

// ---------------- transpose + cast: W fp32 [rows][ldw] -> WT bf16 [cols][ldt] ----------------
__global__ __launch_bounds__(256) void transpose_cast(const float* __restrict__ W, long ldw,
                                                      u16* __restrict__ WT, long ldt) {
    __shared__ float tile[32][33];
    int tx = threadIdx.x, ty = threadIdx.y;    // 32 x 8
    long x = (long)blockIdx.x * 32 + tx;
    long y0 = (long)blockIdx.y * 32;
    for (int r = 0; r < 32; r += 8)
        tile[ty + r][tx] = W[(y0 + ty + r) * ldw + x];
    __syncthreads();
    for (int r = 0; r < 32; r += 8)
        WT[((long)blockIdx.x * 32 + ty + r) * ldt + y0 + tx] = f2bf(tile[tx][ty + r]);
}

// ---------------- cast q-columns of Wqkv (fp32, ld 3072) -> WqC bf16 [1024][1024] ----------------
__global__ __launch_bounds__(256) void cast_q_kernel(const float* __restrict__ Wqkv, u16* __restrict__ WqC) {
    long i = ((long)blockIdx.x * 256 + threadIdx.x) * 4;
    int row = (int)(i >> 10);
    int col = (int)(i & 1023);
    float4 f = *(const float4*)&Wqkv[(long)row * 3072 + col];
    ushort4 o;
    o.x = f2bf(f.x); o.y = f2bf(f.y); o.z = f2bf(f.z); o.w = f2bf(f.w);
    *(ushort4*)&WqC[i] = o;
}

// ======== old GEMM core (kept for the small 1024^3 weight-fuse GEMM): 128x128 tile, 4 waves ========
#define GEMM_PRE()                                                                  \
    __shared__ u16 As[128 * 32];                                                    \
    __shared__ u16 Bs[128 * 32];                                                    \
    const int tid = threadIdx.x;                                                    \
    const int wave = tid >> 6, lane = tid & 63;                                     \
    const int wm = wave >> 1, wn = wave & 1;                                        \
    const int lrow = lane & 15, kq = lane >> 4;                                     \
    const long m0 = (long)blockIdx.y * 128, n0 = (long)blockIdx.x * 128;            \
    const int r0 = wave * 32 + (lane >> 2);                                         \
    const int sg = (lane & 3) ^ ((r0 >> 1) & 3);                                    \
    const u16* a0 = A + (m0 + r0) * lda + sg * 8;                                   \
    const u16* a1 = a0 + 16 * lda;                                                  \
    const u16* b0 = BT + (n0 + r0) * ldb + sg * 8;                                  \
    const u16* b1 = b0 + 16 * ldb;                                                  \
    u16* la0 = &As[(wave * 32) * 32];                                               \
    u16* la1 = &As[(wave * 32 + 16) * 32];                                          \
    u16* lb0 = &Bs[(wave * 32) * 32];                                               \
    u16* lb1 = &Bs[(wave * 32 + 16) * 32];                                          \
    const int acol = (kq ^ ((lrow >> 1) & 3)) * 8;                                  \
    v4f acc[4][4];                                                                  \
    _Pragma("unroll") for (int i = 0; i < 4; i++)                                   \
        _Pragma("unroll") for (int j = 0; j < 4; j++)                               \
            acc[i][j] = (v4f){0.f, 0.f, 0.f, 0.f};                                  \
    for (int k0 = 0; k0 < K; k0 += 32) {                                            \
        gl2lds16(a0 + k0, la0);                                                     \
        gl2lds16(a1 + k0, la1);                                                     \
        gl2lds16(b0 + k0, lb0);                                                     \
        gl2lds16(b1 + k0, lb1);                                                     \
        __syncthreads();                                                            \
        short8 af[4], bf[4];                                                        \
        _Pragma("unroll") for (int i = 0; i < 4; i++)                               \
            af[i] = *(const short8*)&As[(wm * 64 + i * 16 + lrow) * 32 + acol];     \
        _Pragma("unroll") for (int i = 0; i < 4; i++)                               \
            bf[i] = *(const short8*)&Bs[(wn * 64 + i * 16 + lrow) * 32 + acol];     \
        _Pragma("unroll") for (int im = 0; im < 4; im++)                            \
            _Pragma("unroll") for (int in = 0; in < 4; in++)                        \
                acc[im][in] = __builtin_amdgcn_mfma_f32_16x16x32_bf16(af[im], bf[in], acc[im][in], 0, 0, 0); \
        __syncthreads();                                                            \
    }

// ---------------- gemm2: single-output variant (CMODE: 0 = fp32 out, 1 = bf16 out) ----------------
template <int CMODE>
__global__ __launch_bounds__(256) void gemm2(const u16* __restrict__ A, long lda,
                                             const u16* __restrict__ BT, long ldb, int K,
                                             const float* __restrict__ bias,
                                             void* __restrict__ Cptr, long ldc) {
    GEMM_PRE()
#pragma unroll
    for (int im = 0; im < 4; im++) {
#pragma unroll
        for (int in = 0; in < 4; in++) {
            long row = m0 + wm * 64 + im * 16 + kq * 4;
            long col = n0 + wn * 64 + in * 16 + lrow;
            float bv = bias ? bias[col] : 0.f;
#pragma unroll
            for (int i = 0; i < 4; i++) {
                float val = acc[im][in][i] + bv;
                long idx = (row + i) * ldc + col;
                if (CMODE == 0) ((float*)Cptr)[idx] = val;
                else            ((u16*)Cptr)[idx] = f2bf(val);
            }
        }
    }
}

// ======== pipelined 256x256 GEMM engine ========
// 8 waves (2M x 4N), BK=32, 4-deep LDS tile rotation (128 KB), counted vmcnt
// (never 0 in steady state), raw s_barrier (1 per K-step), setprio around MFMA.
//
// LDS swizzle (rule #21 both-sides): gl2lds writes LINEAR LDS; the k-quadrant
// swizzle is applied on the GLOBAL source column (sg) and inverted on the
// ds_read side (acol). Involution: LDS[row][q*8] holds global quadrant
// q ^ ((row>>1)&3). Fragment rows differ only in lrow mod 16 (all wave/frag
// bases are multiples of 16 rows), so acol = (kq ^ ((lrow>>1)&3))*8 is a
// per-thread constant. Without this, row-stride 64B puts 8 lanes per 4-bank
// group -> 8-way conflict (round-1 counters: 9.4M conflicts, MfmaUtil 19%).
//
// Pipeline invariants (race-freedom):
//  - tile t lives in buf t&3; STAGE(t+3) issued in iter t targets buf (t-1)&3,
//    whose reads all retired before the end-of-(t-1) barrier (lgkmcnt enforced
//    by MFMA consumption), and issue happens only after that barrier.
//  - end-of-iter-t wait allows loads of tiles {t+2,t+3} (8) to stay in flight;
//    tile t+1 is guaranteed landed (vmcnt retires in order) before the barrier.
#define WAITV(N) asm volatile("s_waitcnt vmcnt(" #N ")" ::: "memory")

template <int CMODE>   // 0 = fp32 out + bias; 2 = fused kv/gate epilogue
__global__ __launch_bounds__(512, 2) void gemm256(const u16* __restrict__ A, long lda,
                                                  const u16* __restrict__ BT, long ldb, int K,
                                                  const float* __restrict__ bias,
                                                  const float* __restrict__ bias2,
                                                  void* __restrict__ C0, void* __restrict__ C1,
                                                  long ldc) {
    __shared__ u16 smem[4 * 2 * 8192];   // 128 KB: [buf 0..3][A|B][256 rows x 32 k]
    const int tid = threadIdx.x;
    const int wv = tid >> 6, lane = tid & 63;
    const int wm = wv >> 2, wn = wv & 3;          // 2 x 4 wave grid; wave tile 128 x 64
    const int lrow = lane & 15, kq = lane >> 4;
    const long m0 = (long)blockIdx.y * 256, n0 = (long)blockIdx.x * 256;

    // staging: wave wv owns rows wv*32 .. wv*32+31 of both tiles (2 calls of 16 rows each).
    // Global source column is PRE-SWIZZLED; LDS dest stays linear (gl2lds constraint).
    const int srow = wv * 32 + (lane >> 2);
    const int scol = ((lane & 3) ^ ((lane >> 3) & 3)) * 8;   // sg = (lane&3) ^ ((srow>>1)&3)
    const u16* gA0 = A + (m0 + srow) * lda + scol;
    const u16* gA1 = gA0 + 16 * lda;              // +16 rows: (row>>1)&3 unchanged (16/2=8, 8&3=0)
    const u16* gB0 = BT + (n0 + srow) * ldb + scol;
    const u16* gB1 = gB0 + 16 * ldb;
    const int sb = wv * 32 * 32;                  // u16 offset of wave's stage region in a tile

    // fragment read: undo the swizzle
    const int acol = (kq ^ ((lrow >> 1) & 3)) * 8;
    const int aoff = (wm * 128 + lrow) * 32 + acol;
    const int boff = (wn * 64 + lrow) * 32 + acol;

    v4f acc[8][4];
#pragma unroll
    for (int i = 0; i < 8; i++)
#pragma unroll
        for (int j = 0; j < 4; j++) acc[i][j] = (v4f){0.f, 0.f, 0.f, 0.f};

    const int NT = K >> 5;   // K-tiles of 32 (requires K >= 96; K == 1024 here)

#define STAGE256(tt) {                                              \
        const int _kk = (tt) << 5;                                  \
        u16* _p = &smem[(((tt) & 3) * 2) * 8192 + sb];              \
        gl2lds16(gA0 + _kk, _p);                                    \
        gl2lds16(gA1 + _kk, _p + 512);                              \
        gl2lds16(gB0 + _kk, _p + 8192);                             \
        gl2lds16(gB1 + _kk, _p + 8192 + 512); }

    STAGE256(0)
    STAGE256(1)
    STAGE256(2)
    WAITV(8);                        // 12 issued, <=8 outstanding -> tile 0 landed
    __builtin_amdgcn_s_barrier();

    for (int t = 0; t < NT; ++t) {
        if (t + 3 < NT) STAGE256(t + 3)          // issue-early; buffer freed at end of t-1
        const u16* Ab = &smem[((t & 3) * 2) * 8192];
        const u16* Bb = Ab + 8192;
        short8 af[8], bf[4];
#pragma unroll
        for (int i = 0; i < 8; i++) af[i] = *(const short8*)&Ab[aoff + i * 512];
#pragma unroll
        for (int j = 0; j < 4; j++) bf[j] = *(const short8*)&Bb[boff + j * 512];
        __builtin_amdgcn_s_setprio(1);
#pragma unroll
        for (int i = 0; i < 8; i++)
#pragma unroll
            for (int j = 0; j < 4; j++)
                acc[i][j] = __builtin_amdgcn_mfma_f32_16x16x32_bf16(af[i], bf[j], acc[i][j], 0, 0, 0);
        __builtin_amdgcn_s_setprio(0);
        if (t + 3 < NT)      { WAITV(8); }       // tiles t+2,t+3 may stay in flight
        else if (t + 2 < NT) { WAITV(4); }       // only t+2 issued after t+1
        else if (t + 1 < NT) { WAITV(0); }       // nothing issued after t+1: drain
        __builtin_amdgcn_s_barrier();
    }
#undef STAGE256

    // ---- epilogue ----
    if (CMODE == 0) {
        float* C = (float*)C0;
#pragma unroll
        for (int im = 0; im < 8; im++) {
#pragma unroll
            for (int in = 0; in < 4; in++) {
                long row = m0 + wm * 128 + im * 16 + kq * 4;
                long col = n0 + wn * 64 + in * 16 + lrow;
                float bv = bias ? bias[col] : 0.f;
#pragma unroll
                for (int i = 0; i < 4; i++)
                    C[(row + i) * ldc + col] = acc[im][in][i] + bv;
            }
        }
    } else {
        u16* kvC = (u16*)C0;
        u16* gateC = (u16*)C1;
        const bool isGate = (n0 >= 2048);        // BN=256 aligns with the 2048 split
#pragma unroll
        for (int im = 0; im < 8; im++) {
#pragma unroll
            for (int in = 0; in < 4; in++) {
                long row = m0 + wm * 128 + im * 16 + kq * 4;
                long col = n0 + wn * 64 + in * 16 + lrow;
                if (!isGate) {
                    float bv = bias[col];
#pragma unroll
                    for (int i = 0; i < 4; i++)
                        kvC[(row + i) * 2048 + col] = f2bf(acc[im][in][i] + bv);
                } else {
                    long gc = col - 2048;
                    float bv = bias2[gc];
#pragma unroll
                    for (int i = 0; i < 4; i++) {
                        float sgm = 1.0f / (1.0f + expf(-(acc[im][in][i] + bv)));
                        gateC[(row + i) * 1024 + gc] = f2bf(sgm);
                    }
                }
            }
        }
    }
}

// ---------------- kmag[bh][n] = ||k(row,h)|| ----------------
__global__ __launch_bounds__(256) void kmag_kernel(const u16* __restrict__ kv, float* __restrict__ kmag) {
    int tid = threadIdx.x;
    int wave = tid >> 6, lane = tid & 63;
    long gid = (long)blockIdx.x * 4 + wave;   // 0 .. 16384*16-1
    int row = (int)(gid >> 4);
    int h = (int)(gid & 15);
    float kvl = bf2f(kv[(long)row * 2048 + h * 64 + lane]);
    float ss = kvl * kvl;
#pragma unroll
    for (int m = 32; m > 0; m >>= 1) ss += __shfl_xor(ss, m, 64);
    if (lane == 0) {
        int b = row >> 12;
        int n = row & 4095;
        kmag[((long)b * HH + h) * NSEQ + n] = sqrtf(ss);
    }
}

// ---------------- foldv: field_t[bh][cg][n][4] = v * kmag, transposed via LDS tile ----------------
__global__ __launch_bounds__(256) void foldv_kernel(const u16* __restrict__ kv,
                                                    const float* __restrict__ kmag,
                                                    u16* __restrict__ field_t) {
    __shared__ u16 tile[64][72];   // pad 72: 144B row stride (16B-aligned, 4-bank rotation)
    int bh = blockIdx.y;           // 0..63
    int n0 = blockIdx.x * 64;      // 0..4032
    int b = bh >> 4, h = bh & 15;
    int t = threadIdx.x;

    // phase 1: read v rows (coalesced 128B per 4 lanes), scale by kmag, store to LDS tile
    {
        int r = t >> 2;            // row within tile (0..63)
        int c0 = (t & 3) * 16;     // 16 channels
        int n = n0 + r;
        const u16* src = kv + ((long)(b * NSEQ + n)) * 2048 + 1024 + h * 64 + c0;
        uint4 u0 = *(const uint4*)src;
        uint4 u1 = *(const uint4*)(src + 8);
        float km = kmag[(long)bh * NSEQ + n];
        u16 in[16], o[16];
        *(uint4*)&in[0] = u0;
        *(uint4*)&in[8] = u1;
#pragma unroll
        for (int i = 0; i < 16; i++) o[i] = f2bf(bf2f(in[i]) * km);
        *(uint4*)&tile[r][c0] = *(uint4*)&o[0];
        *(uint4*)&tile[r][c0 + 8] = *(uint4*)&o[8];
    }
    __syncthreads();

    // phase 2: write interleaved [cg][n][4] chunks (coalesced 32B/lane)
    {
        int cg = t >> 4;           // 0..15
        int q = t & 15;            // 0..15 -> 4 rows each
        u16 o[16];
#pragma unroll
        for (int j = 0; j < 4; j++) {
            int r = q * 4 + j;
            *(ushort4*)&o[j * 4] = *(const ushort4*)&tile[r][cg * 4];
        }
        u16* dst = field_t + (((long)bh * 16 + cg) * NSEQ + n0 + q * 4) * 4;
        *(uint4*)&dst[0] = *(uint4*)&o[0];
        *(uint4*)&dst[8] = *(uint4*)&o[8];
    }
}

// ---------------- pyramid: 24-tap merged dilated causal conv from field_t ----------------
__global__ __launch_bounds__(512) void pyramid_kernel(const u16* __restrict__ field_t,
                                                      const float* __restrict__ coefTab,
                                                      u16* __restrict__ accp) {
    __shared__ u16 lds4[NSEQ * 4];  // 32KB: 4096 rows x 4 channels, bf16
    int blk = blockIdx.x;
    int bh = blk >> 4;       // 0..63 : b*16+h
    int cg = blk & 15;       // channel group of 4
    int hd0 = cg * 4;
    int h = bh & 15;
    int tid = threadIdx.x;

    float cf[24];
#pragma unroll
    for (int i = 0; i < 24; i++) cf[i] = coefTab[h * 24 + i];

    // stage: contiguous 32 KB copy (fully coalesced 16B per lane)
    const u16* src = field_t + ((long)bh * 16 + cg) * NSEQ * 4;
#pragma unroll
    for (int k = 0; k < 4; k++) {
        long e = ((long)k * 512 + tid) * 8;
        *(uint4*)&lds4[e] = *(const uint4*)&src[e];
    }
    __syncthreads();

    u16* dst = accp + (long)bh * NSEQ * HD + hd0;
    for (int i = 0; i < 8; i++) {
        int n = tid + i * 512;
        float ax = 0.f, ay = 0.f, az = 0.f, aw = 0.f;
#pragma unroll
        for (int tp = 0; tp < 24; tp++) {
            int s = SHIFTS[tp];
            if (n >= s) {
                const ushort4 f = *(const ushort4*)&lds4[(n - s) * 4];
                float c = cf[tp];
                ax += c * bf2f(f.x); ay += c * bf2f(f.y);
                az += c * bf2f(f.z); aw += c * bf2f(f.w);
            }
        }
        ushort4 o;
        o.x = f2bf(ax); o.y = f2bf(ay); o.z = f2bf(az); o.w = f2bf(aw);
        *(ushort4*)&dst[(long)n * HD] = o;
    }
}

// ---------------- couple: sparse skips + head coupling + gate -> A3 bf16 ----------------
__global__ __launch_bounds__(256) void couple_kernel(const u16* __restrict__ accp,
                                                     const u16* __restrict__ gate,
                                                     const float* __restrict__ coupS,
                                                     const float* __restrict__ swbuf,
                                                     u16* __restrict__ A3) {
    __shared__ float tmp[DD];
    __shared__ float cp[256];
    int row = blockIdx.x;
    int b = row >> 12;
    int n = row & 4095;
    int tid = threadIdx.x;
    float sw0 = swbuf[0], sw1 = swbuf[1];
    cp[tid] = coupS[tid];

    int e = tid * 4;
    int j = e >> 6;      // head
    int hd = e & 63;
    const u16* base = accp + (((long)b * HH + j) * NSEQ + n) * HD + hd;
    ushort4 v0 = *(const ushort4*)base;
    float vx = bf2f(v0.x), vy = bf2f(v0.y), vz = bf2f(v0.z), vw = bf2f(v0.w);
    if (n >= 512) {
        ushort4 s1 = *(const ushort4*)(base - 512 * HD);
        vx += sw0 * bf2f(s1.x); vy += sw0 * bf2f(s1.y);
        vz += sw0 * bf2f(s1.z); vw += sw0 * bf2f(s1.w);
    }
    if (n >= 1024) {
        ushort4 s2 = *(const ushort4*)(base - 1024 * HD);
        vx += sw1 * bf2f(s2.x); vy += sw1 * bf2f(s2.y);
        vz += sw1 * bf2f(s2.z); vw += sw1 * bf2f(s2.w);
    }
    tmp[e] = vx; tmp[e + 1] = vy; tmp[e + 2] = vz; tmp[e + 3] = vw;
    __syncthreads();

    float ox = 0.f, oy = 0.f, oz = 0.f, ow = 0.f;
#pragma unroll
    for (int jj = 0; jj < 16; jj++) {
        float c = cp[j * 16 + jj];
        ox += c * tmp[jj * 64 + hd];
        oy += c * tmp[jj * 64 + hd + 1];
        oz += c * tmp[jj * 64 + hd + 2];
        ow += c * tmp[jj * 64 + hd + 3];
    }
    const ushort4 g = *(const ushort4*)&gate[(long)row * DD + e];
    ox *= bf2f(g.x); oy *= bf2f(g.y); oz *= bf2f(g.z); ow *= bf2f(g.w);
    ushort4 o;
    o.x = f2bf(ox); o.y = f2bf(oy); o.z = f2bf(oz); o.w = f2bf(ow);
    *(ushort4*)&A3[(long)row * DD + e] = o;
}

// ---------------- launch ----------------
extern "C" void kernel_launch(void* const* d_in, const int* in_sizes, int n_in,
                              void* d_out, int out_size, void* d_ws, size_t ws_size,
                              hipStream_t stream) {
    const float* x        = (const float*)d_in[0];   // [16384][1024]
    const float* Wqkv     = (const float*)d_in[1];   // [1024][3072]
    const float* bqkv     = (const float*)d_in[2];   // [3072]
    const float* Wout     = (const float*)d_in[3];   // [1024][1024]
    const float* bout     = (const float*)d_in[4];   // [1024]
    const float* Wgate    = (const float*)d_in[5];   // [1024][1024]
    const float* bgate    = (const float*)d_in[6];   // [1024]
    const float* scale_g  = (const float*)d_in[7];   // [11][16]
    const float* skip_w   = (const float*)d_in[8];   // [2]
    const float* coupling = (const float*)d_in[9];   // [16][16]

    char* ws = (char*)d_ws;
    size_t off = 0;
    auto alloc = [&](size_t bytes) { char* p = ws + off; off += (bytes + 255) & ~(size_t)255; return p; };

    u16*   kv      = (u16*)alloc((size_t)MROWS * 2048 * 2);         // 67.1 MB (k: cols 0..1023, v: 1024..2047)
    u16*   gate    = (u16*)alloc((size_t)MROWS * DD * 2);           // 33.6 MB
    u16*   field_t = (u16*)alloc((size_t)BB * HH * NSEQ * HD * 2);  // 33.6 MB (also aliased as xb early)
    u16*   WkvT    = (u16*)alloc((size_t)2048 * 1024 * 2);          // 4.2 MB   } contiguous: fused B^T
    u16*   WfuseT  = (u16*)alloc((size_t)1024 * 1024 * 2);          // 2.1 MB   } rows 2048..3071
    u16*   WgateT  = (u16*)alloc((size_t)1024 * 1024 * 2);          // 2.1 MB
    u16*   WoutT   = (u16*)alloc((size_t)1024 * 1024 * 2);          // 2.1 MB
    u16*   WqC     = (u16*)alloc((size_t)1024 * 1024 * 2);          // 2.1 MB
    float* kmag    = (float*)alloc((size_t)BB * HH * NSEQ * 4);     // 1.0 MB
    float* bfuse   = (float*)alloc(1024 * 4);
    float* coefT   = (float*)alloc(16 * 24 * 4);
    float* coupS   = (float*)alloc(256 * 4);
    float* swbuf   = (float*)alloc(2 * 4);
    // aliases (all within already-counted regions):
    u16*   xb   = field_t;                              // x cast; dead before foldv writes field_t
    u16*   accp = kv;                                   // pyramid out: kv dead after foldv
    u16*   A3   = kv + (size_t)BB * HH * NSEQ * HD;     // second half of kv region
    // total ~147 MB

    // 0) cast x -> bf16
    cast_x_kernel<<<(MROWS * DD) / (256 * 8), 256, 0, stream>>>(x, xb);

    // 1) small prep
    prep_kernel<<<1, 64, 0, stream>>>(scale_g, skip_w, coupling, coefT, coupS, swbuf);
    bfuse_kernel<<<16, 256, 0, stream>>>(bqkv, Wgate, bgate, bfuse);

    // 2) weight transposes/casts (fp32 -> bf16, B^T layout for MFMA)
    transpose_cast<<<dim3(64, 32), dim3(32, 8), 0, stream>>>(Wqkv + 1024, 3072, WkvT, 1024);  // k,v cols
    transpose_cast<<<dim3(32, 32), dim3(32, 8), 0, stream>>>(Wgate, 1024, WgateT, 1024);
    transpose_cast<<<dim3(32, 32), dim3(32, 8), 0, stream>>>(Wout, 1024, WoutT, 1024);
    cast_q_kernel<<<1024, 256, 0, stream>>>(Wqkv, WqC);                                       // q cols, no transpose

    // 3) WfuseT[g][k_in] = sum_j WgateT[g][j] * WqC[k_in][j]  (= (Wqkv_q @ Wgate)^T)
    //    small grid: stays on the 128^2 engine (64 blocks > 16 blocks of the 256^2 engine)
    gemm2<1><<<dim3(8, 8), 256, 0, stream>>>(WgateT, 1024, WqC, 1024, 1024,
                                             (const float*)nullptr, WfuseT, 1024);

    // 4) fused: [kv | gate] = xb @ [Wkv | Wfuse] (+bias; sigmoid on gate part) -- pipelined 256^2 engine
    gemm256<2><<<dim3(12, 64), 512, 0, stream>>>(xb, 1024, WkvT, 1024, 1024,
                                                 bqkv + 1024, bfuse, kv, gate, 0);

    // 5) kmag
    kmag_kernel<<<(MROWS * HH) / 4, 256, 0, stream>>>(kv, kmag);

    // 6) foldv: field_t[bh][cg][n][4] = v * kmag  (xb dead now)
    foldv_kernel<<<dim3(64, 64), 256, 0, stream>>>(kv, kmag, field_t);

    // 7) pyramid (24 merged taps) -> accp (kv region; kv dead)
    pyramid_kernel<<<BB * HH * 16, 512, 0, stream>>>(field_t, coefT, accp);

    // 8) skips + coupling + gating -> A3 (upper half of kv region)
    couple_kernel<<<MROWS, 256, 0, stream>>>(accp, gate, coupS, swbuf, A3);

    // 9) out = A3 @ Wout + bout  (fp32 out) -- pipelined 256^2 engine
    gemm256<0><<<dim3(4, 64), 512, 0, stream>>>(A3, 1024, WoutT, 1024, 1024,
                                                bout, (const float*)nullptr, (float*)d_out, nullptr, 1024);
}